// Round 1
// baseline (8712.215 us; speedup 1.0000x reference)
//
#include <hip/hip_runtime.h>
#include <math.h>

#define H 512
#define STEPS 1024
#define OUTN 11
#define CWGS 48   // 16 WGs chain0 + 32 WGs chain1

// ---------------- GEMM NT: C[M,N] (+)= A[M,K] * B[N,K]^T ----------------
#define GBM 64
#define GBN 64
#define GBK 64
#define GLD 76   // padded LDS row stride (76%32=12 -> 2-way conflicts only, float4-aligned)

__global__ __launch_bounds__(256, 2)
void gemm_nt(const float* __restrict__ A, const float* __restrict__ B,
             float* __restrict__ C, const float* __restrict__ bias,
             int M, int N, int K, int kPerSplit, int atomicOut)
{
  __shared__ float As[GBM][GLD];
  __shared__ float Bs[GBN][GLD];
  const int mt = blockIdx.x, nt = blockIdx.y, sp = blockIdx.z;
  const int tid = threadIdx.x;
  const int tx = tid & 15, ty = tid >> 4;
  const int k0 = sp * kPerSplit;
  const int kEnd = (k0 + kPerSplit < K) ? (k0 + kPerSplit) : K;

  float acc[4][4] = {{0.f}};

  for (int kb = k0; kb < kEnd; kb += GBK) {
#pragma unroll
    for (int i = 0; i < 4; ++i) {
      int r = ty + i * 16;
      int gk = kb + tx * 4;
      const float* ar = A + (size_t)(mt * GBM + r) * K;
      const float* br = B + (size_t)(nt * GBN + r) * K;
      float4 av, bv;
      if (gk + 4 <= kEnd) {
        av = *(const float4*)(ar + gk);
        bv = *(const float4*)(br + gk);
      } else {
        float at[4], bt[4];
        for (int e = 0; e < 4; ++e) {
          at[e] = (gk + e < kEnd) ? ar[gk + e] : 0.f;
          bt[e] = (gk + e < kEnd) ? br[gk + e] : 0.f;
        }
        av = make_float4(at[0], at[1], at[2], at[3]);
        bv = make_float4(bt[0], bt[1], bt[2], bt[3]);
      }
      *(float4*)&As[r][tx * 4] = av;
      *(float4*)&Bs[r][tx * 4] = bv;
    }
    __syncthreads();
#pragma unroll
    for (int k4 = 0; k4 < GBK; k4 += 4) {
      float4 a[4], b[4];
#pragma unroll
      for (int i = 0; i < 4; ++i) a[i] = *(const float4*)&As[ty * 4 + i][k4];
#pragma unroll
      for (int j = 0; j < 4; ++j) b[j] = *(const float4*)&Bs[tx * 4 + j][k4];
#pragma unroll
      for (int i = 0; i < 4; ++i)
#pragma unroll
        for (int j = 0; j < 4; ++j) {
          acc[i][j] = fmaf(a[i].x, b[j].x, acc[i][j]);
          acc[i][j] = fmaf(a[i].y, b[j].y, acc[i][j]);
          acc[i][j] = fmaf(a[i].z, b[j].z, acc[i][j]);
          acc[i][j] = fmaf(a[i].w, b[j].w, acc[i][j]);
        }
    }
    __syncthreads();
  }

#pragma unroll
  for (int i = 0; i < 4; ++i) {
    int m = mt * GBM + ty * 4 + i;
#pragma unroll
    for (int j = 0; j < 4; ++j) {
      int n = nt * GBN + tx * 4 + j;
      if (atomicOut) {
        atomicAdd(&C[(size_t)m * N + n], acc[i][j]);
      } else {
        float bv = bias ? bias[n] : 0.f;
        C[(size_t)m * N + n] = acc[i][j] + bv;
      }
    }
  }
}

// ---------------- init x_proj with broadcast bias ----------------
__global__ void init_xproj(float* __restrict__ xp, const float* __restrict__ b_in) {
  int i = blockIdx.x * 256 + threadIdx.x;   // exactly 1024*512 threads
  xp[i] = b_in[i & (H - 1)];
}

// ---------------- output projection ----------------
__global__ void out_proj(const float* __restrict__ hs1, const float* __restrict__ Wout,
                         const float* __restrict__ bout, float* __restrict__ out) {
  int idx = blockIdx.x * 256 + threadIdx.x;
  if (idx >= STEPS * OUTN) return;
  int t = idx / OUTN, o = idx - t * OUTN;
  const float* h = hs1 + t * H;
  const float* wr = Wout + o * H;
  float acc = 0.f;
#pragma unroll 4
  for (int i = 0; i < H; i += 4) {
    float4 hv = *(const float4*)(h + i);
    float4 wv = *(const float4*)(wr + i);
    acc = fmaf(hv.x, wv.x, acc);
    acc = fmaf(hv.y, wv.y, acc);
    acc = fmaf(hv.z, wv.z, acc);
    acc = fmaf(hv.w, wv.w, acc);
  }
  out[idx] = acc + bout[o];
}

// ---------------- persistent pipelined double-chain LSTM ----------------
__device__ __forceinline__ float sigm(float x) { return 1.f / (1.f + __expf(-x)); }

// Roles: WG 0..15 = chain0 (layer 0): gates = gx0[t] + Whh0*h0 + bhh0.
//        WG 16..47 = chain1 (layer 1): gates = [Whh1|Wih1]*[h1_prev; h0_t] + bih1 + bhh1,
//        running one tick behind chain0 in the same barrier group.
// h broadcast via double-buffered agent-scope atomics (hbuf[parity][512]); a WG can
// never be 2 barriers ahead, so parity buffers can't be overwritten before being read.
__global__ __launch_bounds__(512, 1)
void lstm_chains(const float* __restrict__ gx0,
                 const float* __restrict__ Whh0, const float* __restrict__ bhh0,
                 const float* __restrict__ Wih1, const float* __restrict__ Whh1,
                 const float* __restrict__ bih1, const float* __restrict__ bhh1,
                 float* __restrict__ hs1, float* __restrict__ out,
                 unsigned* __restrict__ cnt,
                 float* __restrict__ hbuf0, float* __restrict__ hbuf1)
{
  const int wg = blockIdx.x;
  const int tid = threadIdx.x;
  const bool role0 = (wg < 16);

  int lr, ch, gate, ul, unit, grow;
  const float* wsrc;
  float bias;
  if (role0) {
    lr = tid >> 2; ch = tid & 3;          // 128 rows/WG, 4 threads/row, chunk=128 of K=512
    gate = lr >> 5; ul = lr & 31;
    unit = (wg << 5) + ul;
    grow = (gate << 9) + unit;
    wsrc = Whh0 + (size_t)grow * H + ch * 128;
    bias = bhh0[grow];
  } else {
    lr = tid >> 3; ch = tid & 7;          // 64 rows/WG, 8 threads/row, chunk=128 of K=1024
    gate = lr >> 4; ul = lr & 15;
    unit = ((wg - 16) << 4) + ul;
    grow = (gate << 9) + unit;
    if (ch < 4) wsrc = Whh1 + (size_t)grow * H + ch * 128;        // pairs h1_prev
    else        wsrc = Wih1 + (size_t)grow * H + (ch - 4) * 128;  // pairs h0_t
    bias = bih1[grow] + bhh1[grow];
  }

  // weights live in VGPRs for all 1024 steps
  float w[128];
#pragma unroll
  for (int i = 0; i < 128; i += 4) {
    float4 v = *(const float4*)(wsrc + i);
    w[i] = v.x; w[i + 1] = v.y; w[i + 2] = v.z; w[i + 3] = v.w;
  }

  __shared__ float hl[1024];   // [h_prev] (role0) or [h1_prev ; h0_t] (role1)
  __shared__ float gbuf[128];
  __shared__ float gxb[128];

  float c_state = 0.f, h_last = 0.f;
  const int nunits = role0 ? 32 : 16;

  for (int tau = 0; tau <= STEPS; ++tau) {
    if (tau > 0) {
      if (tid == 0) {
        unsigned target = (unsigned)(CWGS * tau);
        while (__hip_atomic_load(cnt, __ATOMIC_ACQUIRE, __HIP_MEMORY_SCOPE_AGENT) < target) {}
      }
      __syncthreads();
    }
    const bool active = role0 ? (tau < STEPS) : (tau > 0);
    if (active) {
      const int t = role0 ? tau : (tau - 1);
      // stage h (+ gx row) into LDS
      if (role0) {
        hl[tid] = __hip_atomic_load(&hbuf0[((t - 1) & 1) * H + tid],
                                    __ATOMIC_RELAXED, __HIP_MEMORY_SCOPE_AGENT);
        if (tid < 128)
          gxb[tid] = gx0[t * 2048 + ((tid >> 5) << 9) + (wg << 5) + (tid & 31)];
      } else {
        hl[tid] = __hip_atomic_load(&hbuf1[((t - 1) & 1) * H + tid],
                                    __ATOMIC_RELAXED, __HIP_MEMORY_SCOPE_AGENT);
        hl[H + tid] = __hip_atomic_load(&hbuf0[(t & 1) * H + tid],
                                        __ATOMIC_RELAXED, __HIP_MEMORY_SCOPE_AGENT);
      }
      __syncthreads();
      // matvec: 128 register-resident weights x LDS h-chunk
      float acc = 0.f;
      const float* hc = &hl[ch * 128];
#pragma unroll
      for (int i = 0; i < 128; i += 4) {
        float4 hv = *(const float4*)(hc + i);
        acc = fmaf(w[i],     hv.x, acc);
        acc = fmaf(w[i + 1], hv.y, acc);
        acc = fmaf(w[i + 2], hv.z, acc);
        acc = fmaf(w[i + 3], hv.w, acc);
      }
      acc += __shfl_xor(acc, 1);
      acc += __shfl_xor(acc, 2);
      if (!role0) acc += __shfl_xor(acc, 4);
      if (ch == 0) gbuf[lr] = acc + bias + (role0 ? gxb[lr] : 0.f);
      __syncthreads();
      if (tid < nunits) {
        int u = role0 ? ((wg << 5) + tid) : (((wg - 16) << 4) + tid);
        float gi = gbuf[tid];
        float gf = gbuf[nunits + tid];
        float gg = gbuf[2 * nunits + tid];
        float go = gbuf[3 * nunits + tid];
        c_state = sigm(gf) * c_state + sigm(gi) * tanhf(gg);
        float hv = sigm(go) * tanhf(c_state);
        h_last = hv;
        if (role0) {
          __hip_atomic_store(&hbuf0[(t & 1) * H + u], hv,
                             __ATOMIC_RELAXED, __HIP_MEMORY_SCOPE_AGENT);
        } else {
          hs1[t * H + u] = hv;
          __hip_atomic_store(&hbuf1[(t & 1) * H + u], hv,
                             __ATOMIC_RELAXED, __HIP_MEMORY_SCOPE_AGENT);
        }
      }
    }
    // arrive (cell stores are wave 0; release fetch_add drains them first)
    if (tid == 0)
      __hip_atomic_fetch_add(cnt, 1u, __ATOMIC_RELEASE, __HIP_MEMORY_SCOPE_AGENT);
  }

  // finals: hn at [11264, 12288), cn at [12288, 13312)
  if (tid < nunits) {
    int uu = role0 ? ((wg << 5) + tid) : (((wg - 16) << 4) + tid);
    int lay = role0 ? 0 : 1;
    out[STEPS * OUTN + lay * H + uu] = h_last;
    out[STEPS * OUTN + 2 * H + lay * H + uu] = c_state;
  }
}

// ---------------- host launch ----------------
extern "C" void kernel_launch(void* const* d_in, const int* in_sizes, int n_in,
                              void* d_out, int out_size, void* d_ws, size_t ws_size,
                              hipStream_t stream)
{
  (void)in_sizes; (void)n_in; (void)out_size; (void)ws_size;
  const float* inputs = (const float*)d_in[0];
  const float* W_in   = (const float*)d_in[1];
  const float* b_in   = (const float*)d_in[2];
  const float* Wih0   = (const float*)d_in[3];
  const float* Whh0   = (const float*)d_in[4];
  const float* bih0   = (const float*)d_in[5];
  const float* bhh0   = (const float*)d_in[6];
  const float* Wih1   = (const float*)d_in[7];
  const float* Whh1   = (const float*)d_in[8];
  const float* bih1   = (const float*)d_in[9];
  const float* bhh1   = (const float*)d_in[10];
  const float* W_out  = (const float*)d_in[11];
  const float* b_out  = (const float*)d_in[12];
  float* out = (float*)d_out;
  float* ws = (float*)d_ws;

  // workspace layout (floats)
  float* xp  = ws;                        // 1024*512
  float* gx0 = ws + 524288;               // 1024*2048
  float* hs1 = ws + 524288 + 2097152;     // 1024*512
  char* syncb = (char*)(ws + 3145728);    // 12 MB offset
  unsigned* cnt = (unsigned*)syncb;
  float* hbuf0 = (float*)(syncb + 256);            // [2][512]
  float* hbuf1 = (float*)(syncb + 256 + 4096);     // [2][512]

  // zero barrier counter + h broadcast buffers (ws is poisoned before each launch)
  hipMemsetAsync(syncb, 0, 16384, stream);

  // x_proj = inputs @ W_in.T + b_in   (split-K atomic GEMM into bias-initialized buffer)
  init_xproj<<<2048, 256, 0, stream>>>(xp, b_in);
  {
    dim3 g(16, 8, 8);
    gemm_nt<<<g, 256, 0, stream>>>(inputs, W_in, xp, nullptr, 1024, 512, 19296, 2412, 1);
  }
  // gx0 = x_proj @ Wih0.T + bih0
  {
    dim3 g(16, 32, 1);
    gemm_nt<<<g, 256, 0, stream>>>(xp, Wih0, gx0, bih0, 1024, 2048, 512, 512, 0);
  }
  // pipelined persistent double-chain recurrence
  lstm_chains<<<CWGS, 512, 0, stream>>>(gx0, Whh0, bhh0, Wih1, Whh1, bih1, bhh1,
                                        hs1, out, cnt, hbuf0, hbuf1);
  // outputs = hs1 @ W_out.T + b_out
  out_proj<<<44, 256, 0, stream>>>(hs1, W_out, b_out, out);
}

// Round 2
// 4359.127 us; speedup vs baseline: 1.9986x; 1.9986x over previous
//
#include <hip/hip_runtime.h>
#include <math.h>

typedef unsigned long long ull;

#define H 512
#define STEPS 1024
#define OUTN 11

// ---------------- GEMM NT: C[M,N] (+)= A[M,K] * B[N,K]^T ----------------
#define GBM 64
#define GBN 64
#define GBK 64
#define GLD 76

__global__ __launch_bounds__(256, 2)
void gemm_nt(const float* __restrict__ A, const float* __restrict__ B,
             float* __restrict__ C, const float* __restrict__ bias,
             int M, int N, int K, int kPerSplit, int atomicOut)
{
  __shared__ float As[GBM][GLD];
  __shared__ float Bs[GBN][GLD];
  const int mt = blockIdx.x, nt = blockIdx.y, sp = blockIdx.z;
  const int tid = threadIdx.x;
  const int tx = tid & 15, ty = tid >> 4;
  const int k0 = sp * kPerSplit;
  const int kEnd = (k0 + kPerSplit < K) ? (k0 + kPerSplit) : K;

  float acc[4][4] = {{0.f}};

  for (int kb = k0; kb < kEnd; kb += GBK) {
#pragma unroll
    for (int i = 0; i < 4; ++i) {
      int r = ty + i * 16;
      int gk = kb + tx * 4;
      const float* ar = A + (size_t)(mt * GBM + r) * K;
      const float* br = B + (size_t)(nt * GBN + r) * K;
      float4 av, bv;
      if (gk + 4 <= kEnd) {
        av = *(const float4*)(ar + gk);
        bv = *(const float4*)(br + gk);
      } else {
        float at[4], bt[4];
        for (int e = 0; e < 4; ++e) {
          at[e] = (gk + e < kEnd) ? ar[gk + e] : 0.f;
          bt[e] = (gk + e < kEnd) ? br[gk + e] : 0.f;
        }
        av = make_float4(at[0], at[1], at[2], at[3]);
        bv = make_float4(bt[0], bt[1], bt[2], bt[3]);
      }
      *(float4*)&As[r][tx * 4] = av;
      *(float4*)&Bs[r][tx * 4] = bv;
    }
    __syncthreads();
#pragma unroll
    for (int k4 = 0; k4 < GBK; k4 += 4) {
      float4 a[4], b[4];
#pragma unroll
      for (int i = 0; i < 4; ++i) a[i] = *(const float4*)&As[ty * 4 + i][k4];
#pragma unroll
      for (int j = 0; j < 4; ++j) b[j] = *(const float4*)&Bs[tx * 4 + j][k4];
#pragma unroll
      for (int i = 0; i < 4; ++i)
#pragma unroll
        for (int j = 0; j < 4; ++j) {
          acc[i][j] = fmaf(a[i].x, b[j].x, acc[i][j]);
          acc[i][j] = fmaf(a[i].y, b[j].y, acc[i][j]);
          acc[i][j] = fmaf(a[i].z, b[j].z, acc[i][j]);
          acc[i][j] = fmaf(a[i].w, b[j].w, acc[i][j]);
        }
    }
    __syncthreads();
  }

#pragma unroll
  for (int i = 0; i < 4; ++i) {
    int m = mt * GBM + ty * 4 + i;
#pragma unroll
    for (int j = 0; j < 4; ++j) {
      int n = nt * GBN + tx * 4 + j;
      if (atomicOut) {
        atomicAdd(&C[(size_t)m * N + n], acc[i][j]);
      } else {
        float bv = bias ? bias[n] : 0.f;
        C[(size_t)m * N + n] = acc[i][j] + bv;
      }
    }
  }
}

__global__ void init_xproj(float* __restrict__ xp, const float* __restrict__ b_in) {
  int i = blockIdx.x * 256 + threadIdx.x;
  xp[i] = b_in[i & (H - 1)];
}

__global__ void out_proj(const float* __restrict__ hs1, const float* __restrict__ Wout,
                         const float* __restrict__ bout, float* __restrict__ out) {
  int idx = blockIdx.x * 256 + threadIdx.x;
  if (idx >= STEPS * OUTN) return;
  int t = idx / OUTN, o = idx - t * OUTN;
  const float* h = hs1 + t * H;
  const float* wr = Wout + o * H;
  float acc = 0.f;
#pragma unroll 4
  for (int i = 0; i < H; i += 4) {
    float4 hv = *(const float4*)(h + i);
    float4 wv = *(const float4*)(wr + i);
    acc = fmaf(hv.x, wv.x, acc);
    acc = fmaf(hv.y, wv.y, acc);
    acc = fmaf(hv.z, wv.z, acc);
    acc = fmaf(hv.w, wv.w, acc);
  }
  out[idx] = acc + bout[o];
}

// ---------------- persistent dataflow double-chain LSTM ----------------
__device__ __forceinline__ float sigm(float x) { return 1.f / (1.f + __expf(-x)); }
__device__ __forceinline__ ull ld_pair(const ull* p) {
  return __hip_atomic_load((ull*)p, __ATOMIC_RELAXED, __HIP_MEMORY_SCOPE_AGENT);
}
__device__ __forceinline__ void st_pair(ull* p, ull v) {
  __hip_atomic_store(p, v, __ATOMIC_RELAXED, __HIP_MEMORY_SCOPE_AGENT);
}

// hb0/hb1: depth-4 ring of (fp32 value | u32 tag) pairs, tag = tick+1, slot = tick&3.
// Init (memset 0) == "tick -1 produced" (h=0, tag=0). No fences, no RMW: the tag
// travels atomically with the data in one 8B relaxed agent store; consumers poll
// their own pair. flags1: chain1 per-WG progress (round index), throttles chain0's
// ring reuse (slack 3 -> off the critical path in steady state).
__global__ __launch_bounds__(512, 1)
void lstm_chains(const float* __restrict__ gx0,
                 const float* __restrict__ Whh0, const float* __restrict__ bhh0,
                 const float* __restrict__ Wih1, const float* __restrict__ Whh1,
                 const float* __restrict__ bih1, const float* __restrict__ bhh1,
                 float* __restrict__ hs1, float* __restrict__ out,
                 ull* __restrict__ hb0, ull* __restrict__ hb1,
                 int* __restrict__ flags1)
{
  const int wg = blockIdx.x;
  const int tid = threadIdx.x;
  const bool role0 = (wg < 16);

  int lr, ch, grow;
  const float* wsrc;
  float bias;
  if (role0) {
    lr = tid >> 2; ch = tid & 3;          // 128 rows/WG, 4 thr/row, chunk 128 of K=512
    int gate = lr >> 5, ul = lr & 31;
    grow = (gate << 9) + (wg << 5) + ul;
    wsrc = Whh0 + (size_t)grow * H + ch * 128;
    bias = bhh0[grow];
  } else {
    lr = tid >> 3; ch = tid & 7;          // 64 rows/WG, 8 thr/row, chunk 128 of K=1024
    int gate = lr >> 4, ul = lr & 15;
    grow = (gate << 9) + ((wg - 16) << 4) + ul;
    if (ch < 4) wsrc = Whh1 + (size_t)grow * H + ch * 128;        // h1_prev chunks
    else        wsrc = Wih1 + (size_t)grow * H + (ch - 4) * 128;  // h0_t chunks
    bias = bih1[grow] + bhh1[grow];
  }

  float w[128];
#pragma unroll
  for (int i = 0; i < 128; i += 4) {
    float4 v = *(const float4*)(wsrc + i);
    w[i] = v.x; w[i + 1] = v.y; w[i + 2] = v.z; w[i + 3] = v.w;
  }

  // chunk-padded LDS: chunk c at offset c*132 -> chunk bases hit banks 0,4,8,...,28
  __shared__ float hl[8 * 132];
  __shared__ float gbuf[128];
  __shared__ float gxb[128];

  float c_state = 0.f, h_last = 0.f;

  if (role0) {
    const int myslot = ((tid >> 7) * 132) + (tid & 127);
    for (int t = 0; t < STEPS; ++t) {
      // poll h0[t-1]: slot (t-1)&3, tag t
      const ull* src = hb0 + (((unsigned)(t + 3) & 3u) << 9) + tid;
      ull p;
      do { p = ld_pair(src); } while ((unsigned)(p >> 32) != (unsigned)t);
      hl[myslot] = __uint_as_float((unsigned)p);
      if (tid < 128)
        gxb[tid] = gx0[t * 2048 + ((tid >> 5) << 9) + (wg << 5) + (tid & 31)];
      __syncthreads();

      float acc = 0.f;
      const float* hc = &hl[ch * 132];
#pragma unroll
      for (int i = 0; i < 128; i += 4) {
        float4 hv = *(const float4*)(hc + i);
        acc = fmaf(w[i],     hv.x, acc);
        acc = fmaf(w[i + 1], hv.y, acc);
        acc = fmaf(w[i + 2], hv.z, acc);
        acc = fmaf(w[i + 3], hv.w, acc);
      }
      acc += __shfl_xor(acc, 1);
      acc += __shfl_xor(acc, 2);
      if (ch == 0) gbuf[lr] = acc + bias + gxb[lr];
      __syncthreads();

      if (tid < 64) {                      // wave0 only
        float hv = 0.f;
        if (tid < 32) {
          float gi = gbuf[tid];
          float gf = gbuf[32 + tid];
          float gg = gbuf[64 + tid];
          float go = gbuf[96 + tid];
          c_state = sigm(gf) * c_state + sigm(gi) * tanhf(gg);
          hv = sigm(go) * tanhf(c_state);
          h_last = hv;
        }
        // ring-reuse throttle: chain1 must have finished round t-3
        int need = t - 3;
        if (need > 0) {
          int f;
          do {
            f = (tid < 32) ? __hip_atomic_load(&flags1[tid], __ATOMIC_RELAXED,
                                               __HIP_MEMORY_SCOPE_AGENT)
                           : 0x7fffffff;
          } while (!__all(f >= need));
        }
        if (tid < 32) {
          ull pay = ((ull)(unsigned)(t + 1) << 32) | (ull)__float_as_uint(hv);
          st_pair(hb0 + (((unsigned)t & 3u) << 9) + (wg << 5) + tid, pay);
        }
      }
      // no bottom barrier: next round's LDS writes are gated by own tag t+1
    }
  } else {
    const int s1 = ((tid >> 7) * 132) + (tid & 127);
    const int s0 = s1 + 4 * 132;
    for (int tau = 1; tau <= STEPS; ++tau) {
      const int t = tau - 1;
      // need h1[t-1] (slot (t-1)&3, tag t) and h0[t] (slot t&3, tag t+1)
      const ull* q1 = hb1 + (((unsigned)(t + 3) & 3u) << 9) + tid;
      const ull* q0 = hb0 + (((unsigned)t & 3u) << 9) + tid;
      ull p0, p1;
      for (;;) {
        p1 = ld_pair(q1);
        p0 = ld_pair(q0);
        if ((unsigned)(p1 >> 32) == (unsigned)t &&
            (unsigned)(p0 >> 32) == (unsigned)(t + 1)) break;
      }
      hl[s1] = __uint_as_float((unsigned)p1);
      hl[s0] = __uint_as_float((unsigned)p0);
      __syncthreads();

      float acc = 0.f;
      const float* hc = &hl[ch * 132];
#pragma unroll
      for (int i = 0; i < 128; i += 4) {
        float4 hv = *(const float4*)(hc + i);
        acc = fmaf(w[i],     hv.x, acc);
        acc = fmaf(w[i + 1], hv.y, acc);
        acc = fmaf(w[i + 2], hv.z, acc);
        acc = fmaf(w[i + 3], hv.w, acc);
      }
      acc += __shfl_xor(acc, 1);
      acc += __shfl_xor(acc, 2);
      acc += __shfl_xor(acc, 4);
      if (ch == 0) gbuf[lr] = acc + bias;
      __syncthreads();

      if (tid < 16) {
        int u = ((wg - 16) << 4) + tid;
        float gi = gbuf[tid];
        float gf = gbuf[16 + tid];
        float gg = gbuf[32 + tid];
        float go = gbuf[48 + tid];
        c_state = sigm(gf) * c_state + sigm(gi) * tanhf(gg);
        float hv = sigm(go) * tanhf(c_state);
        h_last = hv;
        hs1[t * H + u] = hv;               // plain cached store; flushed at kernel end
        ull pay = ((ull)(unsigned)(t + 1) << 32) | (ull)__float_as_uint(hv);
        st_pair(hb1 + (((unsigned)t & 3u) << 9) + u, pay);
      }
      if (tid == 0)
        __hip_atomic_store(&flags1[wg - 16], tau, __ATOMIC_RELAXED,
                           __HIP_MEMORY_SCOPE_AGENT);
    }
  }

  // finals: hn at [11264, 12288), cn at [12288, 13312)
  const int nunits = role0 ? 32 : 16;
  if (tid < nunits) {
    int uu = role0 ? ((wg << 5) + tid) : (((wg - 16) << 4) + tid);
    int lay = role0 ? 0 : 1;
    out[STEPS * OUTN + lay * H + uu] = h_last;
    out[STEPS * OUTN + 2 * H + lay * H + uu] = c_state;
  }
}

// ---------------- host launch ----------------
extern "C" void kernel_launch(void* const* d_in, const int* in_sizes, int n_in,
                              void* d_out, int out_size, void* d_ws, size_t ws_size,
                              hipStream_t stream)
{
  (void)in_sizes; (void)n_in; (void)out_size; (void)ws_size;
  const float* inputs = (const float*)d_in[0];
  const float* W_in   = (const float*)d_in[1];
  const float* b_in   = (const float*)d_in[2];
  const float* Wih0   = (const float*)d_in[3];
  const float* Whh0   = (const float*)d_in[4];
  const float* bih0   = (const float*)d_in[5];
  const float* bhh0   = (const float*)d_in[6];
  const float* Wih1   = (const float*)d_in[7];
  const float* Whh1   = (const float*)d_in[8];
  const float* bih1   = (const float*)d_in[9];
  const float* bhh1   = (const float*)d_in[10];
  const float* W_out  = (const float*)d_in[11];
  const float* b_out  = (const float*)d_in[12];
  float* out = (float*)d_out;
  float* ws = (float*)d_ws;

  float* xp  = ws;                        // 1024*512
  float* gx0 = ws + 524288;               // 1024*2048
  float* hs1 = ws + 524288 + 2097152;     // 1024*512
  char* syncb = (char*)(ws + 3145728);
  ull* hb0 = (ull*)syncb;                 // 4*512 pairs = 16 KB
  ull* hb1 = (ull*)(syncb + 16384);       // 4*512 pairs = 16 KB
  int* flags1 = (int*)(syncb + 32768);    // 32 ints

  hipMemsetAsync(syncb, 0, 33024, stream);

  init_xproj<<<2048, 256, 0, stream>>>(xp, b_in);
  {
    dim3 g(16, 8, 8);
    gemm_nt<<<g, 256, 0, stream>>>(inputs, W_in, xp, nullptr, 1024, 512, 19296, 2412, 1);
  }
  {
    dim3 g(16, 32, 1);
    gemm_nt<<<g, 256, 0, stream>>>(xp, Wih0, gx0, bih0, 1024, 2048, 512, 512, 0);
  }
  lstm_chains<<<48, 512, 0, stream>>>(gx0, Whh0, bhh0, Wih1, Whh1, bih1, bhh1,
                                      hs1, out, hb0, hb1, flags1);
  out_proj<<<44, 256, 0, stream>>>(hs1, W_out, b_out, out);
}

// Round 3
// 3581.772 us; speedup vs baseline: 2.4324x; 1.2170x over previous
//
#include <hip/hip_runtime.h>
#include <math.h>

typedef unsigned long long ull;
typedef unsigned int u32;
typedef unsigned short u16;
typedef _Float16 half2v __attribute__((ext_vector_type(2)));
typedef __bf16 bf16x8 __attribute__((ext_vector_type(8)));
typedef float f32x4 __attribute__((ext_vector_type(4)));

#define H 512
#define STEPS 1024
#define OUTN 11

__device__ __forceinline__ float sigm(float x) { return 1.f / (1.f + __expf(-x)); }
__device__ __forceinline__ ull ld_pair(const ull* p) {
  return __hip_atomic_load((ull*)p, __ATOMIC_RELAXED, __HIP_MEMORY_SCOPE_AGENT);
}
__device__ __forceinline__ void st_pair(ull* p, ull v) {
  __hip_atomic_store(p, v, __ATOMIC_RELAXED, __HIP_MEMORY_SCOPE_AGENT);
}
__device__ __forceinline__ float dot2acc(half2v a, half2v b, float c) {
#if __has_builtin(__builtin_amdgcn_fdot2)
  return __builtin_amdgcn_fdot2(a, b, c, false);
#else
  return c + (float)a.x * (float)b.x + (float)a.y * (float)b.y;
#endif
}
__device__ __forceinline__ u16 f16bits(float x) {
  return __builtin_bit_cast(u16, (_Float16)x);
}
__device__ __forceinline__ half2v bch2(u32 u) { return __builtin_bit_cast(half2v, u); }

// ---------- in-place fp32 -> {bf16 hi, bf16 lo} repack (same 4B/elem) ----------
__device__ __forceinline__ u32 split_bf16(float x) {
  u32 u = __float_as_uint(x);
  u32 rh = (u + 0x7FFFu + ((u >> 16) & 1u)) & 0xFFFF0000u;   // RN bf16 of x
  float hf = __uint_as_float(rh);
  float lo = x - hf;
  u32 ul = __float_as_uint(lo);
  u32 rl = (ul + 0x7FFFu + ((ul >> 16) & 1u)) & 0xFFFF0000u;
  return (rh >> 16) | rl;   // low16 = hi, high16 = lo
}

__global__ void cvt_split(float* __restrict__ A, float* __restrict__ B, int nA, int n4) {
  int idx = blockIdx.x * 256 + threadIdx.x;
  if (idx >= n4) return;
  int base = idx * 4;
  float* p = (base < nA) ? (A + base) : (B + (base - nA));
  float4 v = *(float4*)p;
  u32 r0 = split_bf16(v.x), r1 = split_bf16(v.y), r2 = split_bf16(v.z), r3 = split_bf16(v.w);
  uint4 o = make_uint4(r0, r1, r2, r3);
  *(uint4*)p = o;
}

// ---------- MFMA hi/lo bf16 GEMM: xp[M,N] += A[M,K] * B[N,K]^T (split-K atomic) ----------
__global__ __launch_bounds__(256, 2)
void gemm_hilo(const u32* __restrict__ A2, const u32* __restrict__ B2,
               float* __restrict__ C, int M, int N, int K)
{
  __shared__ __align__(16) u16 Ah[64 * 32], Al[64 * 32], Bh[64 * 32], Bl[64 * 32];
  const int z = blockIdx.z;
  const int zstart = z * 151;                 // splits: 151,151,151,150 (x32 = 19296)
  const int nsteps = (z < 3) ? 151 : 150;
  const int mt = blockIdx.x * 64, nt = blockIdx.y * 64;
  const int tid = threadIdx.x;
  const int row = tid >> 2, cg = (tid & 3) * 8;
  const int wave = tid >> 6, lane = tid & 63;
  const int wm = (wave & 1) * 32, wn = (wave >> 1) * 32;
  const int quad = lane >> 4, l16 = lane & 15;

  f32x4 acc[2][2];
#pragma unroll
  for (int i = 0; i < 2; ++i)
#pragma unroll
    for (int j = 0; j < 2; ++j) acc[i][j] = (f32x4)0.f;

  for (int s = 0; s < nsteps; ++s) {
    const int kb = (zstart + s) * 32;
    // stage A,B tiles: hi-plane + lo-plane
    {
      const u32* ap = A2 + (size_t)(mt + row) * K + kb + cg;
      const u32* bp = B2 + (size_t)(nt + row) * K + kb + cg;
      uint4 a0 = *(const uint4*)ap, a1 = *(const uint4*)(ap + 4);
      uint4 b0 = *(const uint4*)bp, b1 = *(const uint4*)(bp + 4);
      uint4 hi, lo;
      hi = make_uint4((a0.x & 0xFFFF) | (a0.y << 16), (a0.z & 0xFFFF) | (a0.w << 16),
                      (a1.x & 0xFFFF) | (a1.y << 16), (a1.z & 0xFFFF) | (a1.w << 16));
      lo = make_uint4((a0.x >> 16) | (a0.y & 0xFFFF0000u), (a0.z >> 16) | (a0.w & 0xFFFF0000u),
                      (a1.x >> 16) | (a1.y & 0xFFFF0000u), (a1.z >> 16) | (a1.w & 0xFFFF0000u));
      *(uint4*)&Ah[row * 32 + cg] = hi;
      *(uint4*)&Al[row * 32 + cg] = lo;
      hi = make_uint4((b0.x & 0xFFFF) | (b0.y << 16), (b0.z & 0xFFFF) | (b0.w << 16),
                      (b1.x & 0xFFFF) | (b1.y << 16), (b1.z & 0xFFFF) | (b1.w << 16));
      lo = make_uint4((b0.x >> 16) | (b0.y & 0xFFFF0000u), (b0.z >> 16) | (b0.w & 0xFFFF0000u),
                      (b1.x >> 16) | (b1.y & 0xFFFF0000u), (b1.z >> 16) | (b1.w & 0xFFFF0000u));
      *(uint4*)&Bh[row * 32 + cg] = hi;
      *(uint4*)&Bl[row * 32 + cg] = lo;
    }
    __syncthreads();
    bf16x8 ah[2], al[2], bh[2], bl[2];
#pragma unroll
    for (int mf = 0; mf < 2; ++mf) {
      int r = (wm + mf * 16 + l16) * 32 + quad * 8;
      ah[mf] = *reinterpret_cast<const bf16x8*>(&Ah[r]);
      al[mf] = *reinterpret_cast<const bf16x8*>(&Al[r]);
    }
#pragma unroll
    for (int nf = 0; nf < 2; ++nf) {
      int r = (wn + nf * 16 + l16) * 32 + quad * 8;
      bh[nf] = *reinterpret_cast<const bf16x8*>(&Bh[r]);
      bl[nf] = *reinterpret_cast<const bf16x8*>(&Bl[r]);
    }
#pragma unroll
    for (int mf = 0; mf < 2; ++mf)
#pragma unroll
      for (int nf = 0; nf < 2; ++nf) {
        acc[mf][nf] = __builtin_amdgcn_mfma_f32_16x16x32_bf16(ah[mf], bh[nf], acc[mf][nf], 0, 0, 0);
        acc[mf][nf] = __builtin_amdgcn_mfma_f32_16x16x32_bf16(ah[mf], bl[nf], acc[mf][nf], 0, 0, 0);
        acc[mf][nf] = __builtin_amdgcn_mfma_f32_16x16x32_bf16(al[mf], bh[nf], acc[mf][nf], 0, 0, 0);
      }
    __syncthreads();
  }

#pragma unroll
  for (int mf = 0; mf < 2; ++mf)
#pragma unroll
    for (int nf = 0; nf < 2; ++nf)
#pragma unroll
      for (int r = 0; r < 4; ++r) {
        int rw = mt + wm + mf * 16 + quad * 4 + r;
        int cl = nt + wn + nf * 16 + l16;
        atomicAdd(&C[(size_t)rw * N + cl], acc[mf][nf][r]);
      }
}

// ---------------- fp32 GEMM NT (for gx0 = xp @ Wih0^T + bih0) ----------------
#define GBM 64
#define GBN 64
#define GBK 64
#define GLD 76

__global__ __launch_bounds__(256, 2)
void gemm_nt(const float* __restrict__ A, const float* __restrict__ B,
             float* __restrict__ C, const float* __restrict__ bias,
             int M, int N, int K)
{
  __shared__ float As[GBM][GLD];
  __shared__ float Bs[GBN][GLD];
  const int mt = blockIdx.x, nt = blockIdx.y;
  const int tid = threadIdx.x;
  const int tx = tid & 15, ty = tid >> 4;

  float acc[4][4] = {{0.f}};

  for (int kb = 0; kb < K; kb += GBK) {
#pragma unroll
    for (int i = 0; i < 4; ++i) {
      int r = ty + i * 16;
      int gk = kb + tx * 4;
      *(float4*)&As[r][tx * 4] = *(const float4*)(A + (size_t)(mt * GBM + r) * K + gk);
      *(float4*)&Bs[r][tx * 4] = *(const float4*)(B + (size_t)(nt * GBN + r) * K + gk);
    }
    __syncthreads();
#pragma unroll
    for (int k4 = 0; k4 < GBK; k4 += 4) {
      float4 a[4], b[4];
#pragma unroll
      for (int i = 0; i < 4; ++i) a[i] = *(const float4*)&As[ty * 4 + i][k4];
#pragma unroll
      for (int j = 0; j < 4; ++j) b[j] = *(const float4*)&Bs[tx * 4 + j][k4];
#pragma unroll
      for (int i = 0; i < 4; ++i)
#pragma unroll
        for (int j = 0; j < 4; ++j) {
          acc[i][j] = fmaf(a[i].x, b[j].x, acc[i][j]);
          acc[i][j] = fmaf(a[i].y, b[j].y, acc[i][j]);
          acc[i][j] = fmaf(a[i].z, b[j].z, acc[i][j]);
          acc[i][j] = fmaf(a[i].w, b[j].w, acc[i][j]);
        }
    }
    __syncthreads();
  }

#pragma unroll
  for (int i = 0; i < 4; ++i) {
    int m = mt * GBM + ty * 4 + i;
#pragma unroll
    for (int j = 0; j < 4; ++j) {
      int n = nt * GBN + tx * 4 + j;
      C[(size_t)m * N + n] = acc[i][j] + bias[n];
    }
  }
}

__global__ void init_xproj(float* __restrict__ xp, const float* __restrict__ b_in) {
  int i = blockIdx.x * 256 + threadIdx.x;
  xp[i] = b_in[i & (H - 1)];
}

__global__ void out_proj(const float* __restrict__ hs1, const float* __restrict__ Wout,
                         const float* __restrict__ bout, float* __restrict__ out) {
  int idx = blockIdx.x * 256 + threadIdx.x;
  if (idx >= STEPS * OUTN) return;
  int t = idx / OUTN, o = idx - t * OUTN;
  const float* h = hs1 + t * H;
  const float* wr = Wout + o * H;
  float acc = 0.f;
#pragma unroll 4
  for (int i = 0; i < H; i += 4) {
    float4 hv = *(const float4*)(h + i);
    float4 wv = *(const float4*)(wr + i);
    acc = fmaf(hv.x, wv.x, acc);
    acc = fmaf(hv.y, wv.y, acc);
    acc = fmaf(hv.z, wv.z, acc);
    acc = fmaf(hv.w, wv.w, acc);
  }
  out[idx] = acc + bout[o];
}

// ---------------- persistent dataflow double-chain LSTM (f16 dot2, R=8) ----------------
// WG 0..7  = chain0: units [64w,64w+64). 512 thr = 32 rowgroups(8 rows) x 16 chunks(32 of K=512).
// WG 8..23 = chain1: units [32w',+32).   512 thr = 16 rowgroups(8 rows) x 32 chunks(32 of K=1024=[h1;h0]).
// h broadcast: 256 pairs (tag32 | f16 hi unit | f16 lo unit), depth-4 ring, relaxed agent atomics.
__global__ __launch_bounds__(512, 1)
void lstm_chains(const float* __restrict__ gx0,
                 const float* __restrict__ Whh0, const float* __restrict__ bhh0,
                 const float* __restrict__ Wih1, const float* __restrict__ Whh1,
                 const float* __restrict__ bih1, const float* __restrict__ bhh1,
                 float* __restrict__ hs1, float* __restrict__ out,
                 ull* __restrict__ hb0, ull* __restrict__ hb1,
                 int* __restrict__ flags1)
{
  const int wg = blockIdx.x;
  const int tid = threadIdx.x;
  const bool role0 = (wg < 8);

  __shared__ __align__(16) u32 hl_u[512];
  __shared__ __align__(16) float gbuf[256];
  __shared__ __align__(16) float gxb[256];

  half2v wgt[8][16];
  float bias[8];
  int rg, ch;

  if (role0) {
    rg = tid >> 4; ch = tid & 15;                   // rg<32, ch<16
    int g = rg >> 3, lub = (rg & 7) * 8;            // rows rg*8.. stay in one 64-block
    int growb = (g << 9) + (wg << 6) + lub;
    const float* wb = Whh0 + (size_t)growb * H + ch * 32;
#pragma unroll
    for (int r = 0; r < 8; ++r) {
      const float* wr = wb + (size_t)r * H;
#pragma unroll
      for (int j4 = 0; j4 < 8; ++j4) {
        float4 f = *(const float4*)(wr + j4 * 4);
        wgt[r][2 * j4]     = half2v{(_Float16)f.x, (_Float16)f.y};
        wgt[r][2 * j4 + 1] = half2v{(_Float16)f.z, (_Float16)f.w};
      }
      bias[r] = bhh0[growb + r];
    }
  } else {
    rg = tid >> 5; ch = tid & 31;                   // rg<16, ch<32
    int g = rg >> 2, lub = (rg & 3) * 8;
    int growb = (g << 9) + ((wg - 8) << 5) + lub;
    const float* wb = (ch < 16) ? (Whh1 + (size_t)growb * H + ch * 32)
                                : (Wih1 + (size_t)growb * H + (ch - 16) * 32);
#pragma unroll
    for (int r = 0; r < 8; ++r) {
      const float* wr = wb + (size_t)r * H;
#pragma unroll
      for (int j4 = 0; j4 < 8; ++j4) {
        float4 f = *(const float4*)(wr + j4 * 4);
        wgt[r][2 * j4]     = half2v{(_Float16)f.x, (_Float16)f.y};
        wgt[r][2 * j4 + 1] = half2v{(_Float16)f.z, (_Float16)f.w};
      }
      bias[r] = bih1[growb + r] + bhh1[growb + r];
    }
  }

  float c_state = 0.f, h_last = 0.f;

  if (role0) {
    const int w = wg;
    for (int t = 0; t < STEPS; ++t) {
      // lanes 256..511 prefetch gx0 rows for this WG's 64 units (4 gates x 64)
      if (tid >= 256) {
        int j = tid - 256;
        gxb[j] = gx0[t * 2048 + ((j >> 6) << 9) + (w << 6) + (j & 63)];
      } else {
        // poll h0[t-1]: slot (t-1)&3, tag t
        const ull* src = hb0 + (((unsigned)(t + 3) & 3u) << 8) + tid;
        ull p;
        do { p = ld_pair(src); } while ((unsigned)(p >> 32) != (unsigned)t);
        hl_u[tid] = (u32)p;
      }
      __syncthreads();

      float accv[8];
#pragma unroll
      for (int r = 0; r < 8; ++r) accv[r] = 0.f;
      {
        const u32* hp = hl_u + (ch << 4);
        uint4 q0 = *(const uint4*)hp;
        uint4 q1 = *(const uint4*)(hp + 4);
        uint4 q2 = *(const uint4*)(hp + 8);
        uint4 q3 = *(const uint4*)(hp + 12);
        half2v h2[16] = {bch2(q0.x), bch2(q0.y), bch2(q0.z), bch2(q0.w),
                         bch2(q1.x), bch2(q1.y), bch2(q1.z), bch2(q1.w),
                         bch2(q2.x), bch2(q2.y), bch2(q2.z), bch2(q2.w),
                         bch2(q3.x), bch2(q3.y), bch2(q3.z), bch2(q3.w)};
#pragma unroll
        for (int j = 0; j < 16; ++j)
#pragma unroll
          for (int r = 0; r < 8; ++r)
            accv[r] = dot2acc(wgt[r][j], h2[j], accv[r]);
      }
#pragma unroll
      for (int o = 1; o < 16; o <<= 1)
#pragma unroll
        for (int r = 0; r < 8; ++r)
          accv[r] += __shfl_xor(accv[r], o);
      if (ch == 0) {
        float4 ga = *(const float4*)&gxb[rg * 8];
        float4 gb = *(const float4*)&gxb[rg * 8 + 4];
        float4 o0 = make_float4(accv[0] + bias[0] + ga.x, accv[1] + bias[1] + ga.y,
                                accv[2] + bias[2] + ga.z, accv[3] + bias[3] + ga.w);
        float4 o1 = make_float4(accv[4] + bias[4] + gb.x, accv[5] + bias[5] + gb.y,
                                accv[6] + bias[6] + gb.z, accv[7] + bias[7] + gb.w);
        *(float4*)&gbuf[rg * 8] = o0;
        *(float4*)&gbuf[rg * 8 + 4] = o1;
      }
      __syncthreads();

      if (tid < 64) {
        float gi = gbuf[tid], gf = gbuf[64 + tid], gg = gbuf[128 + tid], go = gbuf[192 + tid];
        c_state = sigm(gf) * c_state + sigm(gi) * tanhf(gg);
        float hv = sigm(go) * tanhf(c_state);
        h_last = hv;
        // ring-reuse throttle: chain1 must have finished round t-3
        int need = t - 3;
        if (need > 0) {
          int f;
          do {
            f = (tid < 16) ? __hip_atomic_load(&flags1[tid], __ATOMIC_RELAXED,
                                               __HIP_MEMORY_SCOPE_AGENT)
                           : 0x7fffffff;
          } while (!__all(f >= need));
        }
        float hnb = __shfl_down(hv, 1);
        if ((tid & 1) == 0) {
          u32 pay = (u32)f16bits(hv) | ((u32)f16bits(hnb) << 16);
          st_pair(hb0 + (((unsigned)t & 3u) << 8) + (w << 5) + (tid >> 1),
                  ((ull)(unsigned)(t + 1) << 32) | (ull)pay);
        }
      }
    }
  } else {
    const int w1 = wg - 8;
    for (int tau = 1; tau <= STEPS; ++tau) {
      const int t = tau - 1;
      if (tid < 256) {
        // h1[t-1]: slot (t-1)&3, tag t
        const ull* q1 = hb1 + (((unsigned)(t + 3) & 3u) << 8) + tid;
        ull p;
        do { p = ld_pair(q1); } while ((unsigned)(p >> 32) != (unsigned)t);
        hl_u[tid] = (u32)p;
      } else {
        // h0[t]: slot t&3, tag t+1
        const ull* q0 = hb0 + (((unsigned)t & 3u) << 8) + (tid - 256);
        ull p;
        do { p = ld_pair(q0); } while ((unsigned)(p >> 32) != (unsigned)(t + 1));
        hl_u[tid] = (u32)p;
      }
      __syncthreads();

      float accv[8];
#pragma unroll
      for (int r = 0; r < 8; ++r) accv[r] = 0.f;
      {
        const u32* hp = hl_u + (ch << 4);
        uint4 q0 = *(const uint4*)hp;
        uint4 q1 = *(const uint4*)(hp + 4);
        uint4 q2 = *(const uint4*)(hp + 8);
        uint4 q3 = *(const uint4*)(hp + 12);
        half2v h2[16] = {bch2(q0.x), bch2(q0.y), bch2(q0.z), bch2(q0.w),
                         bch2(q1.x), bch2(q1.y), bch2(q1.z), bch2(q1.w),
                         bch2(q2.x), bch2(q2.y), bch2(q2.z), bch2(q2.w),
                         bch2(q3.x), bch2(q3.y), bch2(q3.z), bch2(q3.w)};
#pragma unroll
        for (int j = 0; j < 16; ++j)
#pragma unroll
          for (int r = 0; r < 8; ++r)
            accv[r] = dot2acc(wgt[r][j], h2[j], accv[r]);
      }
#pragma unroll
      for (int o = 1; o < 32; o <<= 1)
#pragma unroll
        for (int r = 0; r < 8; ++r)
          accv[r] += __shfl_xor(accv[r], o);
      if (ch == 0) {
        float4 o0 = make_float4(accv[0] + bias[0], accv[1] + bias[1],
                                accv[2] + bias[2], accv[3] + bias[3]);
        float4 o1 = make_float4(accv[4] + bias[4], accv[5] + bias[5],
                                accv[6] + bias[6], accv[7] + bias[7]);
        *(float4*)&gbuf[rg * 8] = o0;
        *(float4*)&gbuf[rg * 8 + 4] = o1;
      }
      __syncthreads();

      if (tid < 32) {
        int u = (w1 << 5) + tid;
        float gi = gbuf[tid], gf = gbuf[32 + tid], gg = gbuf[64 + tid], go = gbuf[96 + tid];
        c_state = sigm(gf) * c_state + sigm(gi) * tanhf(gg);
        float hv = sigm(go) * tanhf(c_state);
        h_last = hv;
        hs1[t * H + u] = hv;                       // fp32; flushed at kernel end
        float hnb = __shfl_down(hv, 1);
        if ((tid & 1) == 0) {
          u32 pay = (u32)f16bits(hv) | ((u32)f16bits(hnb) << 16);
          st_pair(hb1 + (((unsigned)t & 3u) << 8) + (w1 << 4) + (tid >> 1),
                  ((ull)(unsigned)(t + 1) << 32) | (ull)pay);
        }
      }
      if (tid == 0)
        __hip_atomic_store(&flags1[w1], tau, __ATOMIC_RELAXED, __HIP_MEMORY_SCOPE_AGENT);
    }
  }

  // finals: hn at [11264,12288), cn at [12288,13312)
  if (role0) {
    if (tid < 64) {
      int u = (wg << 6) + tid;
      out[STEPS * OUTN + u] = h_last;
      out[STEPS * OUTN + 2 * H + u] = c_state;
    }
  } else {
    if (tid < 32) {
      int u = ((wg - 8) << 5) + tid;
      out[STEPS * OUTN + H + u] = h_last;
      out[STEPS * OUTN + 3 * H + u] = c_state;
    }
  }
}

// ---------------- host launch ----------------
extern "C" void kernel_launch(void* const* d_in, const int* in_sizes, int n_in,
                              void* d_out, int out_size, void* d_ws, size_t ws_size,
                              hipStream_t stream)
{
  (void)in_sizes; (void)n_in; (void)out_size; (void)ws_size;
  float* inputs = (float*)d_in[0];          // repacked in place each launch
  float* W_in   = (float*)d_in[1];
  const float* b_in   = (const float*)d_in[2];
  const float* Wih0   = (const float*)d_in[3];
  const float* Whh0   = (const float*)d_in[4];
  const float* bih0   = (const float*)d_in[5];
  const float* bhh0   = (const float*)d_in[6];
  const float* Wih1   = (const float*)d_in[7];
  const float* Whh1   = (const float*)d_in[8];
  const float* bih1   = (const float*)d_in[9];
  const float* bhh1   = (const float*)d_in[10];
  const float* W_out  = (const float*)d_in[11];
  const float* b_out  = (const float*)d_in[12];
  float* out = (float*)d_out;
  float* ws = (float*)d_ws;

  float* xp  = ws;                        // 1024*512
  float* gx0 = ws + 524288;               // 1024*2048
  float* hs1 = ws + 524288 + 2097152;     // 1024*512
  char* syncb = (char*)(ws + 3145728);
  ull* hb0 = (ull*)syncb;                 // 4 slots x 256 pairs = 8 KB
  ull* hb1 = (ull*)(syncb + 8192);        // 8 KB
  int* flags1 = (int*)(syncb + 16384);    // 16 ints

  hipMemsetAsync(syncb, 0, 16448, stream);

  // repack inputs + W_in to {bf16 hi, bf16 lo} in place
  {
    const int nA = STEPS * 19296;                 // 19,759,104
    const int n4 = (nA + H * 19296) / 4;          // 7,409,664
    cvt_split<<<n4 / 256, 256, 0, stream>>>(inputs, W_in, nA, n4);
  }
  init_xproj<<<2048, 256, 0, stream>>>(xp, b_in);
  {
    dim3 g(16, 8, 4);
    gemm_hilo<<<g, 256, 0, stream>>>((const u32*)inputs, (const u32*)W_in, xp,
                                     1024, 512, 19296);
  }
  {
    dim3 g(16, 32, 1);
    gemm_nt<<<g, 256, 0, stream>>>(xp, Wih0, gx0, bih0, 1024, 2048, 512);
  }
  lstm_chains<<<24, 512, 0, stream>>>(gx0, Whh0, bhh0, Wih1, Whh1, bih1, bhh1,
                                      hs1, out, hb0, hb1, flags1);
  out_proj<<<44, 256, 0, stream>>>(hs1, W_out, b_out, out);
}

// Round 4
// 3257.224 us; speedup vs baseline: 2.6747x; 1.0996x over previous
//
#include <hip/hip_runtime.h>
#include <math.h>

typedef unsigned long long ull;
typedef unsigned int u32;
typedef unsigned short u16;
typedef _Float16 half2v __attribute__((ext_vector_type(2)));
typedef __bf16 bf16x8 __attribute__((ext_vector_type(8)));
typedef float f32x4 __attribute__((ext_vector_type(4)));

#define H 512
#define STEPS 1024
#define OUTN 11

__device__ __forceinline__ float sigm(float x) { return 1.f / (1.f + __expf(-x)); }
__device__ __forceinline__ ull ld_pair(const ull* p) {
  return __hip_atomic_load((ull*)p, __ATOMIC_RELAXED, __HIP_MEMORY_SCOPE_AGENT);
}
__device__ __forceinline__ void st_pair(ull* p, ull v) {
  __hip_atomic_store(p, v, __ATOMIC_RELAXED, __HIP_MEMORY_SCOPE_AGENT);
}
__device__ __forceinline__ float dot2acc(half2v a, half2v b, float c) {
#if __has_builtin(__builtin_amdgcn_fdot2)
  return __builtin_amdgcn_fdot2(a, b, c, false);
#else
  return c + (float)a.x * (float)b.x + (float)a.y * (float)b.y;
#endif
}
__device__ __forceinline__ u16 f16bits(float x) {
  return __builtin_bit_cast(u16, (_Float16)x);
}
__device__ __forceinline__ half2v bch2(u32 u) { return __builtin_bit_cast(half2v, u); }

// ---------- in-place fp32 -> {bf16 hi, bf16 lo} repack (same 4B/elem) ----------
__device__ __forceinline__ u32 split_bf16(float x) {
  u32 u = __float_as_uint(x);
  u32 rh = (u + 0x7FFFu + ((u >> 16) & 1u)) & 0xFFFF0000u;
  float hf = __uint_as_float(rh);
  float lo = x - hf;
  u32 ul = __float_as_uint(lo);
  u32 rl = (ul + 0x7FFFu + ((ul >> 16) & 1u)) & 0xFFFF0000u;
  return (rh >> 16) | rl;
}

__global__ void cvt_split(float* __restrict__ A, float* __restrict__ B, int nA, int n4) {
  int idx = blockIdx.x * 256 + threadIdx.x;
  if (idx >= n4) return;
  int base = idx * 4;
  float* p = (base < nA) ? (A + base) : (B + (base - nA));
  float4 v = *(float4*)p;
  u32 r0 = split_bf16(v.x), r1 = split_bf16(v.y), r2 = split_bf16(v.z), r3 = split_bf16(v.w);
  uint4 o = make_uint4(r0, r1, r2, r3);
  *(uint4*)p = o;
}

// ---------- MFMA hi/lo bf16 GEMM: xp[M,N] += A[M,K] * B[N,K]^T (split-K atomic) ----------
__global__ __launch_bounds__(256, 2)
void gemm_hilo(const u32* __restrict__ A2, const u32* __restrict__ B2,
               float* __restrict__ C, int M, int N, int K)
{
  __shared__ __align__(16) u16 Ah[64 * 32], Al[64 * 32], Bh[64 * 32], Bl[64 * 32];
  const int z = blockIdx.z;
  const int zstart = z * 151;
  const int nsteps = (z < 3) ? 151 : 150;
  const int mt = blockIdx.x * 64, nt = blockIdx.y * 64;
  const int tid = threadIdx.x;
  const int row = tid >> 2, cg = (tid & 3) * 8;
  const int wave = tid >> 6, lane = tid & 63;
  const int wm = (wave & 1) * 32, wn = (wave >> 1) * 32;
  const int quad = lane >> 4, l16 = lane & 15;

  f32x4 acc[2][2];
#pragma unroll
  for (int i = 0; i < 2; ++i)
#pragma unroll
    for (int j = 0; j < 2; ++j) acc[i][j] = (f32x4)0.f;

  for (int s = 0; s < nsteps; ++s) {
    const int kb = (zstart + s) * 32;
    {
      const u32* ap = A2 + (size_t)(mt + row) * K + kb + cg;
      const u32* bp = B2 + (size_t)(nt + row) * K + kb + cg;
      uint4 a0 = *(const uint4*)ap, a1 = *(const uint4*)(ap + 4);
      uint4 b0 = *(const uint4*)bp, b1 = *(const uint4*)(bp + 4);
      uint4 hi, lo;
      hi = make_uint4((a0.x & 0xFFFF) | (a0.y << 16), (a0.z & 0xFFFF) | (a0.w << 16),
                      (a1.x & 0xFFFF) | (a1.y << 16), (a1.z & 0xFFFF) | (a1.w << 16));
      lo = make_uint4((a0.x >> 16) | (a0.y & 0xFFFF0000u), (a0.z >> 16) | (a0.w & 0xFFFF0000u),
                      (a1.x >> 16) | (a1.y & 0xFFFF0000u), (a1.z >> 16) | (a1.w & 0xFFFF0000u));
      *(uint4*)&Ah[row * 32 + cg] = hi;
      *(uint4*)&Al[row * 32 + cg] = lo;
      hi = make_uint4((b0.x & 0xFFFF) | (b0.y << 16), (b0.z & 0xFFFF) | (b0.w << 16),
                      (b1.x & 0xFFFF) | (b1.y << 16), (b1.z & 0xFFFF) | (b1.w << 16));
      lo = make_uint4((b0.x >> 16) | (b0.y & 0xFFFF0000u), (b0.z >> 16) | (b0.w & 0xFFFF0000u),
                      (b1.x >> 16) | (b1.y & 0xFFFF0000u), (b1.z >> 16) | (b1.w & 0xFFFF0000u));
      *(uint4*)&Bh[row * 32 + cg] = hi;
      *(uint4*)&Bl[row * 32 + cg] = lo;
    }
    __syncthreads();
    bf16x8 ah[2], al[2], bh[2], bl[2];
#pragma unroll
    for (int mf = 0; mf < 2; ++mf) {
      int r = (wm + mf * 16 + l16) * 32 + quad * 8;
      ah[mf] = *reinterpret_cast<const bf16x8*>(&Ah[r]);
      al[mf] = *reinterpret_cast<const bf16x8*>(&Al[r]);
    }
#pragma unroll
    for (int nf = 0; nf < 2; ++nf) {
      int r = (wn + nf * 16 + l16) * 32 + quad * 8;
      bh[nf] = *reinterpret_cast<const bf16x8*>(&Bh[r]);
      bl[nf] = *reinterpret_cast<const bf16x8*>(&Bl[r]);
    }
#pragma unroll
    for (int mf = 0; mf < 2; ++mf)
#pragma unroll
      for (int nf = 0; nf < 2; ++nf) {
        acc[mf][nf] = __builtin_amdgcn_mfma_f32_16x16x32_bf16(ah[mf], bh[nf], acc[mf][nf], 0, 0, 0);
        acc[mf][nf] = __builtin_amdgcn_mfma_f32_16x16x32_bf16(ah[mf], bl[nf], acc[mf][nf], 0, 0, 0);
        acc[mf][nf] = __builtin_amdgcn_mfma_f32_16x16x32_bf16(al[mf], bh[nf], acc[mf][nf], 0, 0, 0);
      }
    __syncthreads();
  }

#pragma unroll
  for (int mf = 0; mf < 2; ++mf)
#pragma unroll
    for (int nf = 0; nf < 2; ++nf)
#pragma unroll
      for (int r = 0; r < 4; ++r) {
        int rw = mt + wm + mf * 16 + quad * 4 + r;
        int cl = nt + wn + nf * 16 + l16;
        atomicAdd(&C[(size_t)rw * N + cl], acc[mf][nf][r]);
      }
}

// ---------------- fp32 GEMM NT (gx0 = xp @ Wih0^T + bih0) ----------------
#define GBM 64
#define GBN 64
#define GBK 64
#define GLD 76

__global__ __launch_bounds__(256, 2)
void gemm_nt(const float* __restrict__ A, const float* __restrict__ B,
             float* __restrict__ C, const float* __restrict__ bias,
             int M, int N, int K)
{
  __shared__ float As[GBM][GLD];
  __shared__ float Bs[GBN][GLD];
  const int mt = blockIdx.x, nt = blockIdx.y;
  const int tid = threadIdx.x;
  const int tx = tid & 15, ty = tid >> 4;

  float acc[4][4] = {{0.f}};

  for (int kb = 0; kb < K; kb += GBK) {
#pragma unroll
    for (int i = 0; i < 4; ++i) {
      int r = ty + i * 16;
      int gk = kb + tx * 4;
      *(float4*)&As[r][tx * 4] = *(const float4*)(A + (size_t)(mt * GBM + r) * K + gk);
      *(float4*)&Bs[r][tx * 4] = *(const float4*)(B + (size_t)(nt * GBN + r) * K + gk);
    }
    __syncthreads();
#pragma unroll
    for (int k4 = 0; k4 < GBK; k4 += 4) {
      float4 a[4], b[4];
#pragma unroll
      for (int i = 0; i < 4; ++i) a[i] = *(const float4*)&As[ty * 4 + i][k4];
#pragma unroll
      for (int j = 0; j < 4; ++j) b[j] = *(const float4*)&Bs[tx * 4 + j][k4];
#pragma unroll
      for (int i = 0; i < 4; ++i)
#pragma unroll
        for (int j = 0; j < 4; ++j) {
          acc[i][j] = fmaf(a[i].x, b[j].x, acc[i][j]);
          acc[i][j] = fmaf(a[i].y, b[j].y, acc[i][j]);
          acc[i][j] = fmaf(a[i].z, b[j].z, acc[i][j]);
          acc[i][j] = fmaf(a[i].w, b[j].w, acc[i][j]);
        }
    }
    __syncthreads();
  }

#pragma unroll
  for (int i = 0; i < 4; ++i) {
    int m = mt * GBM + ty * 4 + i;
#pragma unroll
    for (int j = 0; j < 4; ++j) {
      int n = nt * GBN + tx * 4 + j;
      C[(size_t)m * N + n] = acc[i][j] + bias[n];
    }
  }
}

__global__ void init_xproj(float* __restrict__ xp, const float* __restrict__ b_in) {
  int i = blockIdx.x * 256 + threadIdx.x;
  xp[i] = b_in[i & (H - 1)];
}

__global__ void out_proj(const float* __restrict__ hs1, const float* __restrict__ Wout,
                         const float* __restrict__ bout, float* __restrict__ out) {
  int idx = blockIdx.x * 256 + threadIdx.x;
  if (idx >= STEPS * OUTN) return;
  int t = idx / OUTN, o = idx - t * OUTN;
  const float* h = hs1 + t * H;
  const float* wr = Wout + o * H;
  float acc = 0.f;
#pragma unroll 4
  for (int i = 0; i < H; i += 4) {
    float4 hv = *(const float4*)(h + i);
    float4 wv = *(const float4*)(wr + i);
    acc = fmaf(hv.x, wv.x, acc);
    acc = fmaf(hv.y, wv.y, acc);
    acc = fmaf(hv.z, wv.z, acc);
    acc = fmaf(hv.w, wv.w, acc);
  }
  out[idx] = acc + bout[o];
}

// ---------------- persistent dataflow double-chain LSTM, private mailboxes ----------------
// mb0: h0 pairs, 24 consumer mailboxes x 8 ring slots x 256 pairs (8B each).
// mb1: h1 pairs, 16 consumer mailboxes x 8 ring slots x 256 pairs.
// Each line polled by exactly ONE consumer WG -> no same-line poll pileup at the
// coherence point (R1 measured ~150ns/same-line txn; R2/R3's shared-line polls
// were the 3us/tick floor). Tag travels with data in one 8B relaxed agent store.
#define NC0 24   // consumers of h0 (8 chain0 + 16 chain1)
#define NC1 16   // consumers of h1 (16 chain1)
#define RD 8     // ring depth

__global__ __launch_bounds__(512, 1)
void lstm_chains(const float* __restrict__ gx0,
                 const float* __restrict__ Whh0, const float* __restrict__ bhh0,
                 const float* __restrict__ Wih1, const float* __restrict__ Whh1,
                 const float* __restrict__ bih1, const float* __restrict__ bhh1,
                 float* __restrict__ hs1, float* __restrict__ out,
                 ull* __restrict__ mb0, ull* __restrict__ mb1,
                 int* __restrict__ flags1)
{
  const int wg = blockIdx.x;
  const int tid = threadIdx.x;
  const bool role0 = (wg < 8);

  __shared__ __align__(16) u32 hl_u[512];
  __shared__ __align__(16) float gbuf[256];
  __shared__ __align__(16) float gxb[256];

  half2v wgt[8][16];
  float bias[8];
  int rg, ch;

  if (role0) {
    rg = tid >> 4; ch = tid & 15;
    int g = rg >> 3, lub = (rg & 7) * 8;
    int growb = (g << 9) + (wg << 6) + lub;
    const float* wb = Whh0 + (size_t)growb * H + ch * 32;
#pragma unroll
    for (int r = 0; r < 8; ++r) {
      const float* wr = wb + (size_t)r * H;
#pragma unroll
      for (int j4 = 0; j4 < 8; ++j4) {
        float4 f = *(const float4*)(wr + j4 * 4);
        wgt[r][2 * j4]     = half2v{(_Float16)f.x, (_Float16)f.y};
        wgt[r][2 * j4 + 1] = half2v{(_Float16)f.z, (_Float16)f.w};
      }
      bias[r] = bhh0[growb + r];
    }
  } else {
    rg = tid >> 5; ch = tid & 31;
    int g = rg >> 2, lub = (rg & 3) * 8;
    int growb = (g << 9) + ((wg - 8) << 5) + lub;
    const float* wb = (ch < 16) ? (Whh1 + (size_t)growb * H + ch * 32)
                                : (Wih1 + (size_t)growb * H + (ch - 16) * 32);
#pragma unroll
    for (int r = 0; r < 8; ++r) {
      const float* wr = wb + (size_t)r * H;
#pragma unroll
      for (int j4 = 0; j4 < 8; ++j4) {
        float4 f = *(const float4*)(wr + j4 * 4);
        wgt[r][2 * j4]     = half2v{(_Float16)f.x, (_Float16)f.y};
        wgt[r][2 * j4 + 1] = half2v{(_Float16)f.z, (_Float16)f.w};
      }
      bias[r] = bih1[growb + r] + bhh1[growb + r];
    }
  }

  float c_state = 0.f, h_last = 0.f;

  if (role0) {
    const int w = wg;
    for (int t = 0; t < STEPS; ++t) {
      if (tid >= 256) {
        int j = tid - 256;
        gxb[j] = gx0[t * 2048 + ((j >> 6) << 9) + (w << 6) + (j & 63)];
        // ring-reuse throttle, hoisted OFF the store's critical path:
        // every 4th tick require chain1 past round t-4 (covers overwrites t..t+3).
        if (j < 16 && (t & 3) == 0 && t > 0) {
          int need = t - 4, f;
          do {
            f = __hip_atomic_load(&flags1[j], __ATOMIC_RELAXED, __HIP_MEMORY_SCOPE_AGENT);
          } while (f < need);
        }
      } else {
        // poll private copy of h0[t-1]: slot (t-1)&7, tag t
        const ull* src = mb0 + ((((w << 3) | ((t + RD - 1) & (RD - 1)))) << 8) + tid;
        ull p;
        do { p = ld_pair(src); } while ((unsigned)(p >> 32) != (unsigned)t);
        hl_u[tid] = (u32)p;
      }
      __syncthreads();

      float accv[8];
#pragma unroll
      for (int r = 0; r < 8; ++r) accv[r] = 0.f;
      {
        const u32* hp = hl_u + (ch << 4);
        uint4 q0 = *(const uint4*)hp;
        uint4 q1 = *(const uint4*)(hp + 4);
        uint4 q2 = *(const uint4*)(hp + 8);
        uint4 q3 = *(const uint4*)(hp + 12);
        half2v h2[16] = {bch2(q0.x), bch2(q0.y), bch2(q0.z), bch2(q0.w),
                         bch2(q1.x), bch2(q1.y), bch2(q1.z), bch2(q1.w),
                         bch2(q2.x), bch2(q2.y), bch2(q2.z), bch2(q2.w),
                         bch2(q3.x), bch2(q3.y), bch2(q3.z), bch2(q3.w)};
#pragma unroll
        for (int j = 0; j < 16; ++j)
#pragma unroll
          for (int r = 0; r < 8; ++r)
            accv[r] = dot2acc(wgt[r][j], h2[j], accv[r]);
      }
#pragma unroll
      for (int o = 1; o < 16; o <<= 1)
#pragma unroll
        for (int r = 0; r < 8; ++r)
          accv[r] += __shfl_xor(accv[r], o);
      if (ch == 0) {
        float4 ga = *(const float4*)&gxb[rg * 8];
        float4 gb = *(const float4*)&gxb[rg * 8 + 4];
        float4 o0 = make_float4(accv[0] + bias[0] + ga.x, accv[1] + bias[1] + ga.y,
                                accv[2] + bias[2] + ga.z, accv[3] + bias[3] + ga.w);
        float4 o1 = make_float4(accv[4] + bias[4] + gb.x, accv[5] + bias[5] + gb.y,
                                accv[6] + bias[6] + gb.z, accv[7] + bias[7] + gb.w);
        *(float4*)&gbuf[rg * 8] = o0;
        *(float4*)&gbuf[rg * 8 + 4] = o1;
      }
      __syncthreads();

      if (tid < 64) {
        float gi = gbuf[tid], gf = gbuf[64 + tid], gg = gbuf[128 + tid], go = gbuf[192 + tid];
        c_state = sigm(gf) * c_state + sigm(gi) * tanhf(gg);
        float hv = sigm(go) * tanhf(c_state);
        float hnb = __shfl_down(hv, 1);
        if ((tid & 1) == 0) {
          u32 payl = (u32)f16bits(hv) | ((u32)f16bits(hnb) << 16);
          ull pay = ((ull)(unsigned)(t + 1) << 32) | (ull)payl;
          const int slot = t & (RD - 1);
          const int pidx = (w << 5) + (tid >> 1);
          // fan out to all 24 private mailboxes, ASAP after cell math
#pragma unroll
          for (int c = 0; c < NC0; ++c)
            st_pair(mb0 + (((c << 3) | slot) << 8) + pidx, pay);
        }
        h_last = hv;
      }
    }
  } else {
    const int v = wg - 8;
    for (int tau = 1; tau <= STEPS; ++tau) {
      const int t = tau - 1;
      if (tid < 256) {
        // private copy of h1[t-1]: slot (t-1)&7, tag t
        const ull* q1 = mb1 + ((((v << 3) | ((t + RD - 1) & (RD - 1)))) << 8) + tid;
        ull p;
        do { p = ld_pair(q1); } while ((unsigned)(p >> 32) != (unsigned)t);
        hl_u[tid] = (u32)p;
      } else {
        // private copy of h0[t]: slot t&7, tag t+1, consumer index 8+v
        const ull* q0 = mb0 + (((((8 + v) << 3) | (t & (RD - 1)))) << 8) + (tid - 256);
        ull p;
        do { p = ld_pair(q0); } while ((unsigned)(p >> 32) != (unsigned)(t + 1));
        hl_u[tid] = (u32)p;
      }
      __syncthreads();

      float accv[8];
#pragma unroll
      for (int r = 0; r < 8; ++r) accv[r] = 0.f;
      {
        const u32* hp = hl_u + (ch << 4);
        uint4 q0 = *(const uint4*)hp;
        uint4 q1 = *(const uint4*)(hp + 4);
        uint4 q2 = *(const uint4*)(hp + 8);
        uint4 q3 = *(const uint4*)(hp + 12);
        half2v h2[16] = {bch2(q0.x), bch2(q0.y), bch2(q0.z), bch2(q0.w),
                         bch2(q1.x), bch2(q1.y), bch2(q1.z), bch2(q1.w),
                         bch2(q2.x), bch2(q2.y), bch2(q2.z), bch2(q2.w),
                         bch2(q3.x), bch2(q3.y), bch2(q3.z), bch2(q3.w)};
#pragma unroll
        for (int j = 0; j < 16; ++j)
#pragma unroll
          for (int r = 0; r < 8; ++r)
            accv[r] = dot2acc(wgt[r][j], h2[j], accv[r]);
      }
#pragma unroll
      for (int o = 1; o < 32; o <<= 1)
#pragma unroll
        for (int r = 0; r < 8; ++r)
          accv[r] += __shfl_xor(accv[r], o);
      if (ch == 0) {
        float4 o0 = make_float4(accv[0] + bias[0], accv[1] + bias[1],
                                accv[2] + bias[2], accv[3] + bias[3]);
        float4 o1 = make_float4(accv[4] + bias[4], accv[5] + bias[5],
                                accv[6] + bias[6], accv[7] + bias[7]);
        *(float4*)&gbuf[rg * 8] = o0;
        *(float4*)&gbuf[rg * 8 + 4] = o1;
      }
      __syncthreads();

      if (tid < 32) {
        int u = (v << 5) + tid;
        float gi = gbuf[tid], gf = gbuf[32 + tid], gg = gbuf[64 + tid], go = gbuf[96 + tid];
        c_state = sigm(gf) * c_state + sigm(gi) * tanhf(gg);
        float hv = sigm(go) * tanhf(c_state);
        float hnb = __shfl_down(hv, 1);
        if ((tid & 1) == 0) {
          u32 payl = (u32)f16bits(hv) | ((u32)f16bits(hnb) << 16);
          ull pay = ((ull)(unsigned)(t + 1) << 32) | (ull)payl;
          const int slot = t & (RD - 1);
          const int pidx = (v << 4) + (tid >> 1);
#pragma unroll
          for (int c = 0; c < NC1; ++c)
            st_pair(mb1 + (((c << 3) | slot) << 8) + pidx, pay);
        }
        h_last = hv;
        hs1[t * H + u] = hv;               // plain cached store; flushed at kernel end
      }
      if (tid == 0)
        __hip_atomic_store(&flags1[v], tau, __ATOMIC_RELAXED, __HIP_MEMORY_SCOPE_AGENT);
    }
  }

  // finals: hn at [11264,12288), cn at [12288,13312)
  if (role0) {
    if (tid < 64) {
      int u = (wg << 6) + tid;
      out[STEPS * OUTN + u] = h_last;
      out[STEPS * OUTN + 2 * H + u] = c_state;
    }
  } else {
    if (tid < 32) {
      int u = ((wg - 8) << 5) + tid;
      out[STEPS * OUTN + H + u] = h_last;
      out[STEPS * OUTN + 3 * H + u] = c_state;
    }
  }
}

// ---------------- host launch ----------------
extern "C" void kernel_launch(void* const* d_in, const int* in_sizes, int n_in,
                              void* d_out, int out_size, void* d_ws, size_t ws_size,
                              hipStream_t stream)
{
  (void)in_sizes; (void)n_in; (void)out_size; (void)ws_size;
  float* inputs = (float*)d_in[0];
  float* W_in   = (float*)d_in[1];
  const float* b_in   = (const float*)d_in[2];
  const float* Wih0   = (const float*)d_in[3];
  const float* Whh0   = (const float*)d_in[4];
  const float* bih0   = (const float*)d_in[5];
  const float* bhh0   = (const float*)d_in[6];
  const float* Wih1   = (const float*)d_in[7];
  const float* Whh1   = (const float*)d_in[8];
  const float* bih1   = (const float*)d_in[9];
  const float* bhh1   = (const float*)d_in[10];
  const float* W_out  = (const float*)d_in[11];
  const float* b_out  = (const float*)d_in[12];
  float* out = (float*)d_out;
  float* ws = (float*)d_ws;

  float* xp  = ws;                        // 1024*512
  float* gx0 = ws + 524288;               // 1024*2048
  float* hs1 = ws + 524288 + 2097152;     // 1024*512
  char* syncb = (char*)(ws + 3145728);    // 12 MB offset
  ull* mb0 = (ull*)syncb;                             // 24*8*256*8 = 384 KB
  ull* mb1 = (ull*)(syncb + 24 * 8 * 256 * 8);        // 16*8*256*8 = 256 KB
  int* flags1 = (int*)(syncb + (24 + 16) * 8 * 256 * 8);  // 64 B

  hipMemsetAsync(syncb, 0, (24 + 16) * 8 * 256 * 8 + 64, stream);

  {
    const int nA = STEPS * 19296;
    const int n4 = (nA + H * 19296) / 4;
    cvt_split<<<n4 / 256, 256, 0, stream>>>(inputs, W_in, nA, n4);
  }
  init_xproj<<<2048, 256, 0, stream>>>(xp, b_in);
  {
    dim3 g(16, 8, 4);
    gemm_hilo<<<g, 256, 0, stream>>>((const u32*)inputs, (const u32*)W_in, xp,
                                     1024, 512, 19296);
  }
  {
    dim3 g(16, 32, 1);
    gemm_nt<<<g, 256, 0, stream>>>(xp, Wih0, gx0, bih0, 1024, 2048, 512);
  }
  lstm_chains<<<24, 512, 0, stream>>>(gx0, Whh0, bhh0, Wih1, Whh1, bih1, bhh1,
                                      hs1, out, mb0, mb1, flags1);
  out_proj<<<44, 256, 0, stream>>>(hs1, W_out, b_out, out);
}